// Round 13
// baseline (230.516 us; speedup 1.0000x reference)
//
#include <hip/hip_runtime.h>
#include <stdint.h>

// AudioSNN: conv1(1->32)+spike+pool -> conv2(32->64)+spike+pool -> fc1
// -> 25-step LIF (fc2, fc3).
// conv2, fc1, fc2/fc3 all run on MFMA: activations/spikes are exact small
// integers (exact fp16), weights use an exact 2-way fp16 split (err ~2^-22).
// R19: attack the unprofiled ~103us (fc1+lif). convf is at its structural
// floor (5 falsified micro-levers: R3/R6/R9/R10/R12-pkfma-null).
//   - k_lif: 1 -> 2 blocks/CU (512 blocks x 2 samples). The 25-step loop is
//     barrier-latency-bound; a second independent block per CU hides the
//     stalls. Per-sample arithmetic chains identical; only LDS strides
//     (s-dim 4->2), guards (n16<4 -> n16<2) and grid change.
//   - k_fc1: 64 -> 32 sample tiles (grid 1024, bt 16KB, launch_bounds
//     (256,4) -> 4 blocks/CU, 4 staggered rounds vs 2 lockstep). Per-output
//     MFMA chain (kc order, hi->lo) verbatim; acc [4][4]->[4][2].
// convf/prep verbatim R12 (best measured 187.0us).
// Dead ends (do not revisit): in-block producer/consumer wave split (R3,R9:
// spills), afrag prefetch rotation (R6), setprio (R10), de-fused conv
// (R1-R7), conv1 pk-FMA (R12: null).
// NOTE: WRITE_SIZE inflation is L2 dirty-writeback attribution, not RMW.
// Summation orders frozen (spike thresholds are ulp-sensitive).
//
// ws layout:
//   part f32 [32][1024][256]       @0     32 MB
//   xq   u8  [1024][8192]          @32M    8 MB
//   afrag f16 [9][4][2][512]       @41M   72 KB  (conv2 A fragments hi/lo)
//   w1s  f16 [4096][64][16]        @42M    8 MB  (fc1 A frags, hi/lo inline)

#define NSTEP 25

using half8   = __attribute__((ext_vector_type(8))) _Float16;
using half4v  = __attribute__((ext_vector_type(4))) _Float16;
using half2v  = __attribute__((ext_vector_type(2))) _Float16;
using float4v = __attribute__((ext_vector_type(4))) float;
using float2v = __attribute__((ext_vector_type(2))) float;

__device__ __forceinline__ float lif_update(float mem, float cur) {
#pragma clang fp contract(off)
  float reset = (mem > 1.0f) ? 1.0f : 0.0f;
  float m = 0.95f * mem;
  m = m + cur;
  m = m - reset;
  return m;
}

// magic u8->fp16: perm packs [b, 0x64] halfwords = fp16(1024+b); pk-sub 1024.
// Bit-identical to scalar cvt for b in 0..255.
__device__ __forceinline__ half2v u8pair_to_h2(uint32_t w, uint32_t sel) {
  union { uint32_t u; half2v h; } c;
  c.u = __builtin_amdgcn_perm(w, 0x64646464u, sel);
  return c.h - (half2v){(_Float16)1024.0f, (_Float16)1024.0f};
}
__device__ __forceinline__ half8 u8x8_to_h8(uint32_t w0, uint32_t w1) {
  union { half8 v; half2v p[4]; } u;
  u.p[0] = u8pair_to_h2(w0, 0x00050004u);
  u.p[1] = u8pair_to_h2(w0, 0x00070006u);
  u.p[2] = u8pair_to_h2(w1, 0x00050004u);
  u.p[3] = u8pair_to_h2(w1, 0x00070006u);
  return u.v;
}

// --------------------------------------------------- afrag prep (72 blocks)
__global__ __launch_bounds__(256) void k_prep(const float* __restrict__ w2c,
                                              _Float16* __restrict__ afrag) {
  const int b = blockIdx.x;
  const int t = threadIdx.x;
  if (t < 64) {
    const int tp = b >> 3;
    const int mt = (b & 7) >> 1;
    const int sp = b & 1;
    const int m = t & 15, quad = t >> 4;
#pragma unroll
    for (int j = 0; j < 8; ++j) {
      int ch = quad * 8 + j;
      int oc = mt * 16 + m;
      float wv = w2c[(size_t)(oc * 32 + ch) * 9 + tp];
      float hi = (float)(_Float16)wv;
      _Float16 val = (sp == 0) ? (_Float16)wv : (_Float16)(wv - hi);
      afrag[(size_t)b * 512 + t * 8 + j] = val;
    }
  }
}

// --------------------------------- fused conv1+conv2 + w1s prep (verbatim R12)
__global__ __launch_bounds__(256, 4) void k_convf(const float* __restrict__ x,
                                                  const float* __restrict__ w1c,
                                                  const float* __restrict__ b1c,
                                                  const _Float16* __restrict__ afrag,
                                                  const float* __restrict__ b2c,
                                                  uint8_t* __restrict__ xq,
                                                  const float* __restrict__ w1,
                                                  _Float16* __restrict__ w1s) {
  __shared__ float xin[38 * 34];
  __shared__ _Float16 cin[18 * 18 * 40];
  __shared__ uint8_t cnt[64 * 64];
  __shared__ float wl[288];
  __shared__ float bl[32];
  const int t = threadIdx.x;
  const int b = blockIdx.x;

  if (b < 1024) {                         // ---- w1s prep (leading round)
    const int W = b * 4 + (t >> 6);
    const int lane = t & 63;
    const int mt = W >> 8, kcg = W & 255;
    const int m = lane & 15, quad = lane >> 4;
    const float* src = w1 + (size_t)(mt * 16 + m) * 8192 + kcg * 32 + quad * 8;
    float4 u0 = *(const float4*)src;
    float4 u1 = *(const float4*)(src + 4);
    float wv[8] = {u0.x, u0.y, u0.z, u0.w, u1.x, u1.y, u1.z, u1.w};
    half8 hi, lo;
#pragma unroll
    for (int e = 0; e < 8; ++e) {
      float h = (float)(_Float16)wv[e];
      hi[e] = (_Float16)wv[e];
      lo[e] = (_Float16)(wv[e] - h);
    }
    _Float16* dst = w1s + (size_t)W * 1024 + lane * 16;
    *(half8*)dst = hi;
    *(half8*)(dst + 8) = lo;
    return;
  }

  const int cb = b - 1024;
  const int s = cb >> 1;
  const int h = cb & 1;

  for (int idx = t; idx < 38 * 34; idx += 256) xin[idx] = 0.0f;
  {
    half8* cp = (half8*)cin;
    half8 z = {};
#pragma unroll
    for (int r = 0; r < 7; ++r) {
      int idx = t + r * 256;
      if (idx < 1620) cp[idx] = z;
    }
  }
  wl[t] = w1c[t];
  if (t < 32) { wl[256 + t] = w1c[256 + t]; bl[t] = b1c[t]; }
  __syncthreads();

  {
    const int lr0 = (h == 0) ? 3 : 0;
    const float* xs = x + (size_t)s * 2048 + (h ? 29 * 32 : 0);
    for (int idx = t; idx < 280; idx += 256) {
      int row_i = idx >> 3, q = idx & 7;
      float4 v = *(const float4*)(xs + row_i * 32 + q * 4);
      float* dst = &xin[(lr0 + row_i) * 34 + q * 4 + 1];
      dst[0] = v.x; dst[1] = v.y; dst[2] = v.z; dst[3] = v.w;
    }
  }
  __syncthreads();

  {
    const int ch = t & 31;
    const int po = t >> 5;
    float wc[9];
#pragma unroll
    for (int i = 0; i < 9; ++i) wc[i] = wl[ch * 9 + i];
    const float bv = bl[ch];
    const int pyLo = (h == 0) ? 1 : 0;
    const int pyHi = (h == 0) ? 17 : 16;
    for (int rr = 0; rr < 36; ++rr) {
      int pos = rr * 8 + po;
      int py = pos >> 4, px = pos & 15;
      if (py < pyLo || py > pyHi) continue;
      float p[4][4];
#pragma unroll
      for (int rw = 0; rw < 4; ++rw) {
        float2 a = *(const float2*)&xin[(2 * py + rw) * 34 + 2 * px];
        float2 bq = *(const float2*)&xin[(2 * py + rw) * 34 + 2 * px + 2];
        p[rw][0] = a.x; p[rw][1] = a.y; p[rw][2] = bq.x; p[rw][3] = bq.y;
      }
      float2v acc0 = {0.f, 0.f};
      float2v acc1 = {0.f, 0.f};
#pragma unroll
      for (int ky = 0; ky < 3; ++ky)
#pragma unroll
        for (int kx = 0; kx < 3; ++kx) {
          float w = wc[ky * 3 + kx];
          float2v wv2 = {w, w};
          float2v p0 = {p[ky][kx], p[ky][kx + 1]};
          float2v p1 = {p[1 + ky][kx], p[1 + ky][kx + 1]};
          acc0 = __builtin_elementwise_fma(wv2, p0, acc0);
          acc1 = __builtin_elementwise_fma(wv2, p1, acc1);
        }
      int c = 0;
      c += ((acc0[0] + bv) > 1.0f) ? 1 : 0;
      c += ((acc0[1] + bv) > 1.0f) ? 1 : 0;
      c += ((acc1[0] + bv) > 1.0f) ? 1 : 0;
      c += ((acc1[1] + bv) > 1.0f) ? 1 : 0;
      cin[(py * 18 + px + 1) * 40 + ch] = (_Float16)(float)c;
    }
  }
  __syncthreads();

  const int lane = t & 63;
  const int wave = __builtin_amdgcn_readfirstlane(t >> 6);
  const int xlane = lane & 15, quad = lane >> 4;

  float4v acc[4][4];
#pragma unroll
  for (int mt = 0; mt < 4; ++mt)
#pragma unroll
    for (int nt = 0; nt < 4; ++nt) acc[mt][nt] = (float4v){0.f, 0.f, 0.f, 0.f};

#pragma unroll
  for (int ky = 0; ky < 3; ++ky)
#pragma unroll
    for (int kx = 0; kx < 3; ++kx) {
      const int tp = ky * 3 + kx;
      half8 bfr[4];
#pragma unroll
      for (int nt = 0; nt < 4; ++nt) {
        int row = wave * 4 + nt + ky;
        int col = xlane + kx;
        bfr[nt] = *(const half8*)&cin[(row * 18 + col) * 40 + quad * 8];
      }
#pragma unroll
      for (int mt = 0; mt < 4; ++mt) {
        half8 ah = *(const half8*)(afrag +
                     ((size_t)((tp * 4 + mt) * 2 + 0)) * 512 + lane * 8);
        half8 al = *(const half8*)(afrag +
                     ((size_t)((tp * 4 + mt) * 2 + 1)) * 512 + lane * 8);
#pragma unroll
        for (int nt = 0; nt < 4; ++nt) {
          acc[mt][nt] = __builtin_amdgcn_mfma_f32_16x16x32_f16(ah, bfr[nt],
                                                               acc[mt][nt], 0, 0, 0);
          acc[mt][nt] = __builtin_amdgcn_mfma_f32_16x16x32_f16(al, bfr[nt],
                                                               acc[mt][nt], 0, 0, 0);
        }
      }
    }

  float bw[4][4];
#pragma unroll
  for (int mt = 0; mt < 4; ++mt)
#pragma unroll
    for (int r = 0; r < 4; ++r) bw[mt][r] = b2c[mt * 16 + quad * 4 + r];

  const int px = xlane >> 1;
  const bool writer = (xlane & 1) == 0;
#pragma unroll
  for (int mt = 0; mt < 4; ++mt)
#pragma unroll
    for (int ntp = 0; ntp < 2; ++ntp) {
      int py = wave * 2 + ntp;
#pragma unroll
      for (int r = 0; r < 4; ++r) {
        float v0 = 0.25f * acc[mt][2 * ntp + 0][r] + bw[mt][r];
        float v1 = 0.25f * acc[mt][2 * ntp + 1][r] + bw[mt][r];
        int c = ((v0 > 1.0f) ? 1 : 0) + ((v1 > 1.0f) ? 1 : 0);
        c += __shfl_xor(c, 1, 64);
        if (writer) {
          int oc = mt * 16 + quad * 4 + r;
          cnt[oc * 64 + py * 8 + px] = (uint8_t)c;
        }
      }
    }
  __syncthreads();

  {
    uint4 v = *(const uint4*)&cnt[(t >> 2) * 64 + (t & 3) * 16];
    *(uint4*)(xq + (size_t)s * 8192 + (size_t)(t >> 2) * 128 + h * 64 +
              (t & 3) * 16) = v;
  }
}

// ---------------------------------------------------------------- fc1 (MFMA)
// R19: 32-sample tiles, grid 1024 (32 sblk x 32 kblk), bt 16KB, 4 blocks/CU.
// Per-output MFMA chain (kc 0..7, hi->lo, same fragments) verbatim R12.
__global__ __launch_bounds__(256, 4) void k_fc1(const uint8_t* __restrict__ xq,
                                                const _Float16* __restrict__ w1s,
                                                float* __restrict__ part) {
  __shared__ _Float16 bt[8 * 2 * 64 * 8];   // [kc][nt2][lane][8] = 16 KB
  const int t = threadIdx.x;
  const int sblk = blockIdx.x >> 5;   // 32 sample tiles of 32
  const int kblk = blockIdx.x & 31;   // 32 K slices of 256
  const int sb = sblk * 32;

  {  // stage B: u8 counts -> fp16, frag-ready (magic perm)
    const int row = t >> 3;           // 0..31 (sample within tile)
    const int seg = t & 7;            // 0..7 (32B K-segments)
    const int nt = row >> 4, n16 = row & 15;
    const uint8_t* src = xq + (size_t)(sb + row) * 8192 + kblk * 256 + seg * 32;
#pragma unroll
    for (int q = 0; q < 2; ++q) {
      uint4 u = *(const uint4*)(src + q * 16);
#pragma unroll
      for (int g = 0; g < 2; ++g) {
        half8 h = (g == 0) ? u8x8_to_h8(u.x, u.y) : u8x8_to_h8(u.z, u.w);
        int koff = seg * 32 + q * 16 + g * 8;
        int kc = koff >> 5, quad = (koff >> 3) & 3;
        *(half8*)&bt[(((kc * 2 + nt) * 64) + quad * 16 + n16) * 8] = h;
      }
    }
  }
  __syncthreads();

  const int lane = t & 63;
  const int wave = __builtin_amdgcn_readfirstlane(t >> 6);

  float4v acc[4][2];
#pragma unroll
  for (int mt = 0; mt < 4; ++mt)
#pragma unroll
    for (int nt = 0; nt < 2; ++nt) acc[mt][nt] = (float4v){0.f, 0.f, 0.f, 0.f};

  // W(kc,mt) = (wave*4+mt)*256 + kblk*8+kc ; layout [W][lane][16]
  const _Float16* wbase = w1s + ((size_t)(wave * 4) * 256 + kblk * 8) * 1024 + lane * 16;
  half8 a0 = *(const half8*)(wbase);
  half8 a1 = *(const half8*)(wbase + 8);
#pragma unroll
  for (int kc = 0; kc < 8; ++kc) {
    half8 b[2];
#pragma unroll
    for (int nt = 0; nt < 2; ++nt)
      b[nt] = *(const half8*)&bt[((kc * 2 + nt) * 64 + lane) * 8];
#pragma unroll
    for (int mt = 0; mt < 4; ++mt) {
      half8 n0, n1;
      if (!(kc == 7 && mt == 3)) {
        const int nk = (mt == 3) ? kc + 1 : kc;
        const int nm = (mt == 3) ? 0 : mt + 1;
        const _Float16* np = wbase + ((size_t)(nm * 256 + nk)) * 1024;
        n0 = *(const half8*)np;
        n1 = *(const half8*)(np + 8);
      } else { n0 = a0; n1 = a1; }
#pragma unroll
      for (int nt = 0; nt < 2; ++nt) {
        acc[mt][nt] = __builtin_amdgcn_mfma_f32_16x16x32_f16(a0, b[nt],
                                                             acc[mt][nt], 0, 0, 0);
        acc[mt][nt] = __builtin_amdgcn_mfma_f32_16x16x32_f16(a1, b[nt],
                                                             acc[mt][nt], 0, 0, 0);
      }
      a0 = n0; a1 = n1;
    }
  }

  const int n16 = lane & 15, quad = lane >> 4;
  float* pp = part + (size_t)kblk * (1024 * 256);
#pragma unroll
  for (int mt = 0; mt < 4; ++mt)
#pragma unroll
    for (int nt = 0; nt < 2; ++nt) {
      int s = sb + nt * 16 + n16;
      int ob = wave * 64 + mt * 16 + quad * 4;
      float4 v = {0.25f * acc[mt][nt][0], 0.25f * acc[mt][nt][1],
                  0.25f * acc[mt][nt][2], 0.25f * acc[mt][nt][3]};
      *(float4*)&pp[(size_t)s * 256 + ob] = v;
    }
}

// ---------------------------------------------------------------- LIF recurrence
// R19: 2 samples/block, grid 512 = 2 blocks/CU (barrier-latency hiding).
// Per-sample arithmetic chains identical to R12; only LDS strides (s-dim
// 4->2), guards (n16<4 -> n16<2) and grid decomposition changed.
__global__ __launch_bounds__(512, 4) void k_lif(const float* __restrict__ part,
                                                const float* __restrict__ b1,
                                                const float* __restrict__ w2,   // [128][256]
                                                const float* __restrict__ b2,
                                                const float* __restrict__ w3,   // [10][128]
                                                const float* __restrict__ b3,
                                                float* __restrict__ out) {
  __shared__ float cur3l[512];      // [s2][o256]
  __shared__ _Float16 spk3[640];    // [oct32][s2][8] + pad (reads to 623)
  __shared__ _Float16 spk4[384];    // [oct16][s2][8] + pad (reads to 367)
  const int t = threadIdx.x;
  const int sb = blockIdx.x * 2;    // 2 samples/block
  const int lane = t & 63;
  const int wave = __builtin_amdgcn_readfirstlane(t >> 6);
  const int n16 = lane & 15;
  const int quad = lane >> 4;

  // ---- fc1 reduce: batched loads, deterministic kb-order sum + bias-last
  {
    int s = t >> 8, o = t & 255;    // t = s*256 + o, one value per thread
    const float* pb = part + (size_t)(sb + s) * 256 + o;
    float pv[32];
#pragma unroll
    for (int kb = 0; kb < 32; ++kb)
      pv[kb] = pb[(size_t)kb * (1024 * 256)];
    float sum = 0.0f;
#pragma unroll
    for (int kb = 0; kb < 32; ++kb) sum += pv[kb];
    cur3l[t] = sum + b1[o];
  }

  // ---- fc2 A-frags: A[m=lane&15][k=quad*8+jj], hi/lo exact split
  half8 a2h[8], a2l[8];
  {
    const float* wr = w2 + (size_t)(wave * 16 + n16) * 256 + quad * 8;
#pragma unroll
    for (int kt = 0; kt < 8; ++kt) {
      float4 u0 = *(const float4*)(wr + kt * 32);
      float4 u1 = *(const float4*)(wr + kt * 32 + 4);
      float wv[8] = {u0.x, u0.y, u0.z, u0.w, u1.x, u1.y, u1.z, u1.w};
#pragma unroll
      for (int e = 0; e < 8; ++e) {
        float hi = (float)(_Float16)wv[e];
        a2h[kt][e] = (_Float16)wv[e];
        a2l[kt][e] = (_Float16)(wv[e] - hi);
      }
    }
  }
  const float4 b2v = *(const float4*)(b2 + wave * 16 + quad * 4);
  float mem4[4] = {0.f, 0.f, 0.f, 0.f};

  // ---- fc3 A-frags (wave 0), rows >= 10 zero
  half8 a3h[4], a3l[4];
#pragma unroll
  for (int kt = 0; kt < 4; ++kt) { a3h[kt] = (half8){}; a3l[kt] = (half8){}; }
  if (n16 < 10) {
    const float* wr = w3 + (size_t)n16 * 128 + quad * 8;
#pragma unroll
    for (int kt = 0; kt < 4; ++kt) {
      float4 u0 = *(const float4*)(wr + kt * 32);
      float4 u1 = *(const float4*)(wr + kt * 32 + 4);
      float wv[8] = {u0.x, u0.y, u0.z, u0.w, u1.x, u1.y, u1.z, u1.w};
#pragma unroll
      for (int e = 0; e < 8; ++e) {
        float hi = (float)(_Float16)wv[e];
        a3h[kt][e] = (_Float16)wv[e];
        a3l[kt][e] = (_Float16)(wv[e] - hi);
      }
    }
  }
  float b3r[4];
#pragma unroll
  for (int r = 0; r < 4; ++r) {
    int cls = quad * 4 + r;
    b3r[r] = (cls < 10) ? b3[cls] : 0.0f;
  }
  float mem5[4] = {0.f, 0.f, 0.f, 0.f};

  __syncthreads();

  // ---- phase-1 state: threads 0..63, thread = (oct o = t>>1, sample s = t&1)
  float mem3[8], cur3r[8];
  if (t < 64) {
    const int o = t >> 1, s = t & 1;
    const float* cp = &cur3l[s * 256 + o * 8];
    float4 c0 = *(const float4*)cp;
    float4 c1 = *(const float4*)(cp + 4);
    cur3r[0] = c0.x; cur3r[1] = c0.y; cur3r[2] = c0.z; cur3r[3] = c0.w;
    cur3r[4] = c1.x; cur3r[5] = c1.y; cur3r[6] = c1.z; cur3r[7] = c1.w;
#pragma unroll
    for (int j = 0; j < 8; ++j) mem3[j] = 0.0f;
  }

  for (int step = 0; step < NSTEP; ++step) {
    // ---- fc3 for previous step (spk4[step-1] visible since barrier B)
    if (wave == 0 && step > 0) {
      float4v c0 = {0.f, 0.f, 0.f, 0.f}, c1 = {0.f, 0.f, 0.f, 0.f};
#pragma unroll
      for (int kt = 0; kt < 4; ++kt) {
        half8 b = *(const half8*)&spk4[(kt * 4 + quad) * 16 + n16 * 8];
        c0 = __builtin_amdgcn_mfma_f32_16x16x32_f16(a3h[kt], b, c0, 0, 0, 0);
        c1 = __builtin_amdgcn_mfma_f32_16x16x32_f16(a3l[kt], b, c1, 0, 0, 0);
      }
#pragma unroll
      for (int r = 0; r < 4; ++r) {
        int cls = quad * 4 + r;
        float cur5 = (c0[r] + c1[r]) + b3r[r];
        mem5[r] = lif_update(mem5[r], cur5);
        if (n16 < 2 && cls < 10)
          out[(size_t)(step - 1) * 10240 + (size_t)(sb + n16) * 10 + cls] =
              (mem5[r] > 1.0f) ? 1.0f : 0.0f;
      }
    }
    // ---- phase 1: mem3/spk3 (threads 0..63)
    if (t < 64) {
      const int o = t >> 1, s = t & 1;
      half8 sv;
#pragma unroll
      for (int j = 0; j < 8; ++j) {
        mem3[j] = lif_update(mem3[j], cur3r[j]);
        sv[j] = (_Float16)((mem3[j] > 1.0f) ? 1.0f : 0.0f);
      }
      *(half8*)&spk3[o * 16 + s * 8] = sv;
    }
    __syncthreads();   // A: spk3 visible; wave0 done reading spk4[step-1]
    {
      float4v acc0 = {0.f, 0.f, 0.f, 0.f}, acc1 = {0.f, 0.f, 0.f, 0.f};
#pragma unroll
      for (int kt = 0; kt < 8; ++kt) {
        half8 b = *(const half8*)&spk3[(kt * 4 + quad) * 16 + n16 * 8];
        acc0 = __builtin_amdgcn_mfma_f32_16x16x32_f16(a2h[kt], b, acc0, 0, 0, 0);
        acc1 = __builtin_amdgcn_mfma_f32_16x16x32_f16(a2l[kt], b, acc1, 0, 0, 0);
      }
      if (n16 < 2) {
        half4v pk;
#pragma unroll
        for (int r = 0; r < 4; ++r) {
          float cur4 = (acc0[r] + acc1[r]) + b2v[r];
          mem4[r] = lif_update(mem4[r], cur4);
          pk[r] = (_Float16)((mem4[r] > 1.0f) ? 1.0f : 0.0f);
        }
        *(half4v*)&spk4[(wave * 2 + (quad >> 1)) * 16 + n16 * 8 + (quad & 1) * 4] = pk;
      }
    }
    __syncthreads();   // B: spk4[step] visible
  }

  // ---- final fc3 (step NSTEP-1)
  if (wave == 0) {
    float4v c0 = {0.f, 0.f, 0.f, 0.f}, c1 = {0.f, 0.f, 0.f, 0.f};
#pragma unroll
    for (int kt = 0; kt < 4; ++kt) {
      half8 b = *(const half8*)&spk4[(kt * 4 + quad) * 16 + n16 * 8];
      c0 = __builtin_amdgcn_mfma_f32_16x16x32_f16(a3h[kt], b, c0, 0, 0, 0);
      c1 = __builtin_amdgcn_mfma_f32_16x16x32_f16(a3l[kt], b, c1, 0, 0, 0);
    }
#pragma unroll
    for (int r = 0; r < 4; ++r) {
      int cls = quad * 4 + r;
      float cur5 = (c0[r] + c1[r]) + b3r[r];
      mem5[r] = lif_update(mem5[r], cur5);
      if (n16 < 2 && cls < 10)
        out[(size_t)(NSTEP - 1) * 10240 + (size_t)(sb + n16) * 10 + cls] =
            (mem5[r] > 1.0f) ? 1.0f : 0.0f;
    }
  }
}

// ---------------------------------------------------------------- launcher
extern "C" void kernel_launch(void* const* d_in, const int* in_sizes, int n_in,
                              void* d_out, int out_size, void* d_ws, size_t ws_size,
                              hipStream_t stream) {
  (void)in_sizes; (void)n_in; (void)out_size; (void)ws_size;
  const float* x   = (const float*)d_in[0];
  const float* w1c = (const float*)d_in[1];
  const float* b1c = (const float*)d_in[2];
  const float* w2c = (const float*)d_in[3];
  const float* b2c = (const float*)d_in[4];
  const float* fw1 = (const float*)d_in[5];
  const float* fb1 = (const float*)d_in[6];
  const float* fw2 = (const float*)d_in[7];
  const float* fb2 = (const float*)d_in[8];
  const float* fw3 = (const float*)d_in[9];
  const float* fb3 = (const float*)d_in[10];
  float* out = (float*)d_out;

  char* ws = (char*)d_ws;
  float*    part  = (float*)ws;                       // 32 MB
  uint8_t*  xq    = (uint8_t*)(ws + (32u << 20));     //  8 MB
  _Float16* afrag = (_Float16*)(ws + (41u << 20));    // 72 KB
  _Float16* w1s   = (_Float16*)(ws + (42u << 20));    //  8 MB

  k_prep<<<dim3(72), dim3(256), 0, stream>>>(w2c, afrag);
  k_convf<<<dim3(3072), dim3(256), 0, stream>>>(x, w1c, b1c, afrag, b2c, xq,
                                                fw1, w1s);
  k_fc1<<<dim3(1024), dim3(256), 0, stream>>>(xq, w1s, part);
  k_lif<<<dim3(512), dim3(512), 0, stream>>>(part, fb1, fw2, fb2, fw3, fb3, out);
}

// Round 14
// 185.985 us; speedup vs baseline: 1.2394x; 1.2394x over previous
//
#include <hip/hip_runtime.h>
#include <stdint.h>

// AudioSNN: conv1(1->32)+spike+pool -> conv2(32->64)+spike+pool -> fc1
// -> 25-step LIF (fc2, fc3).
// conv2, fc1, fc2/fc3 all run on MFMA: activations/spikes are exact small
// integers (exact fp16), weights use an exact 2-way fp16 split (err ~2^-22).
// R20: FULL REVERT to the R12/R18 configuration (best measured: 186.995us,
// reproduced twice). R13 post-mortem: halving samples/block in lif/fc1
// DOUBLED total MFMA work (B-operand is a fixed 16-column MFMA tile; per-
// block MFMA count does not shrink with sample count) -> +43.5us. Sample
// tiling at 4 samples/block (lif) and 64-sample tiles (fc1) is the measured
// optimum.
// Dead ends (do not revisit): in-block producer/consumer wave split (R3,R9:
// scratch spills), afrag prefetch rotation (R6), setprio (R10), de-fused
// conv (R1-R7 never beat fusion at system level), conv1 pk-FMA (R12: null),
// smaller sample tiles in lif/fc1 (R13: 2x MFMA work).
// Structural floor analysis: convf ~70us = phase-serialized VALU+MFMA with
// all scheduling levers falsified; lif ~55us = 50-barrier dependency chain
// at its tiling optimum; fc1 ~45us; + prep + 3 launch gaps = ~187us.
// NOTE: WRITE_SIZE inflation is L2 dirty-writeback attribution, not RMW.
// Summation orders frozen (spike thresholds are ulp-sensitive).
//
// ws layout:
//   part f32 [32][1024][256]       @0     32 MB
//   xq   u8  [1024][8192]          @32M    8 MB
//   afrag f16 [9][4][2][512]       @41M   72 KB  (conv2 A fragments hi/lo)
//   w1s  f16 [4096][64][16]        @42M    8 MB  (fc1 A frags, hi/lo inline)

#define NSTEP 25

using half8   = __attribute__((ext_vector_type(8))) _Float16;
using half4v  = __attribute__((ext_vector_type(4))) _Float16;
using half2v  = __attribute__((ext_vector_type(2))) _Float16;
using float4v = __attribute__((ext_vector_type(4))) float;
using float2v = __attribute__((ext_vector_type(2))) float;

__device__ __forceinline__ float lif_update(float mem, float cur) {
#pragma clang fp contract(off)
  float reset = (mem > 1.0f) ? 1.0f : 0.0f;
  float m = 0.95f * mem;
  m = m + cur;
  m = m - reset;
  return m;
}

// magic u8->fp16: perm packs [b, 0x64] halfwords = fp16(1024+b); pk-sub 1024.
// Bit-identical to scalar cvt for b in 0..255.
__device__ __forceinline__ half2v u8pair_to_h2(uint32_t w, uint32_t sel) {
  union { uint32_t u; half2v h; } c;
  c.u = __builtin_amdgcn_perm(w, 0x64646464u, sel);
  return c.h - (half2v){(_Float16)1024.0f, (_Float16)1024.0f};
}
__device__ __forceinline__ half8 u8x8_to_h8(uint32_t w0, uint32_t w1) {
  union { half8 v; half2v p[4]; } u;
  u.p[0] = u8pair_to_h2(w0, 0x00050004u);
  u.p[1] = u8pair_to_h2(w0, 0x00070006u);
  u.p[2] = u8pair_to_h2(w1, 0x00050004u);
  u.p[3] = u8pair_to_h2(w1, 0x00070006u);
  return u.v;
}

// --------------------------------------------------- afrag prep (72 blocks)
__global__ __launch_bounds__(256) void k_prep(const float* __restrict__ w2c,
                                              _Float16* __restrict__ afrag) {
  const int b = blockIdx.x;
  const int t = threadIdx.x;
  if (t < 64) {
    const int tp = b >> 3;
    const int mt = (b & 7) >> 1;
    const int sp = b & 1;
    const int m = t & 15, quad = t >> 4;
#pragma unroll
    for (int j = 0; j < 8; ++j) {
      int ch = quad * 8 + j;
      int oc = mt * 16 + m;
      float wv = w2c[(size_t)(oc * 32 + ch) * 9 + tp];
      float hi = (float)(_Float16)wv;
      _Float16 val = (sp == 0) ? (_Float16)wv : (_Float16)(wv - hi);
      afrag[(size_t)b * 512 + t * 8 + j] = val;
    }
  }
}

// --------------------------------- fused conv1+conv2 + w1s prep
// blocks 0..1023:    fc1 w1s prep ([W][lane][16], hi/lo inline)
// blocks 1024..3071: conv fused, half sample each (cb = b-1024, s = cb>>1,
//                    h = cb&1). Phase 1 (VALU, pk-FMA): conv1+spike+pool ->
//                    cin. Phase 2 (MFMA): implicit GEMM M=64 N=256 K=32x9.
//                    LDS 36.7 KB -> 4 blocks/CU.
__global__ __launch_bounds__(256, 4) void k_convf(const float* __restrict__ x,
                                                  const float* __restrict__ w1c,
                                                  const float* __restrict__ b1c,
                                                  const _Float16* __restrict__ afrag,
                                                  const float* __restrict__ b2c,
                                                  uint8_t* __restrict__ xq,
                                                  const float* __restrict__ w1,
                                                  _Float16* __restrict__ w1s) {
  __shared__ float xin[38 * 34];
  __shared__ _Float16 cin[18 * 18 * 40];
  __shared__ uint8_t cnt[64 * 64];
  __shared__ float wl[288];
  __shared__ float bl[32];
  const int t = threadIdx.x;
  const int b = blockIdx.x;

  if (b < 1024) {                         // ---- w1s prep (leading round)
    const int W = b * 4 + (t >> 6);
    const int lane = t & 63;
    const int mt = W >> 8, kcg = W & 255;
    const int m = lane & 15, quad = lane >> 4;
    const float* src = w1 + (size_t)(mt * 16 + m) * 8192 + kcg * 32 + quad * 8;
    float4 u0 = *(const float4*)src;
    float4 u1 = *(const float4*)(src + 4);
    float wv[8] = {u0.x, u0.y, u0.z, u0.w, u1.x, u1.y, u1.z, u1.w};
    half8 hi, lo;
#pragma unroll
    for (int e = 0; e < 8; ++e) {
      float h = (float)(_Float16)wv[e];
      hi[e] = (_Float16)wv[e];
      lo[e] = (_Float16)(wv[e] - h);
    }
    _Float16* dst = w1s + (size_t)W * 1024 + lane * 16;
    *(half8*)dst = hi;
    *(half8*)(dst + 8) = lo;
    return;
  }

  const int cb = b - 1024;
  const int s = cb >> 1;
  const int h = cb & 1;

  for (int idx = t; idx < 38 * 34; idx += 256) xin[idx] = 0.0f;
  {
    half8* cp = (half8*)cin;
    half8 z = {};
#pragma unroll
    for (int r = 0; r < 7; ++r) {
      int idx = t + r * 256;
      if (idx < 1620) cp[idx] = z;
    }
  }
  wl[t] = w1c[t];
  if (t < 32) { wl[256 + t] = w1c[256 + t]; bl[t] = b1c[t]; }
  __syncthreads();

  {
    const int lr0 = (h == 0) ? 3 : 0;
    const float* xs = x + (size_t)s * 2048 + (h ? 29 * 32 : 0);
    for (int idx = t; idx < 280; idx += 256) {
      int row_i = idx >> 3, q = idx & 7;
      float4 v = *(const float4*)(xs + row_i * 32 + q * 4);
      float* dst = &xin[(lr0 + row_i) * 34 + q * 4 + 1];
      dst[0] = v.x; dst[1] = v.y; dst[2] = v.z; dst[3] = v.w;
    }
  }
  __syncthreads();

  {
    const int ch = t & 31;
    const int po = t >> 5;
    float wc[9];
#pragma unroll
    for (int i = 0; i < 9; ++i) wc[i] = wl[ch * 9 + i];
    const float bv = bl[ch];
    const int pyLo = (h == 0) ? 1 : 0;
    const int pyHi = (h == 0) ? 17 : 16;
    for (int rr = 0; rr < 36; ++rr) {
      int pos = rr * 8 + po;
      int py = pos >> 4, px = pos & 15;
      if (py < pyLo || py > pyHi) continue;
      float p[4][4];
#pragma unroll
      for (int rw = 0; rw < 4; ++rw) {
        float2 a = *(const float2*)&xin[(2 * py + rw) * 34 + 2 * px];
        float2 bq = *(const float2*)&xin[(2 * py + rw) * 34 + 2 * px + 2];
        p[rw][0] = a.x; p[rw][1] = a.y; p[rw][2] = bq.x; p[rw][3] = bq.y;
      }
      float2v acc0 = {0.f, 0.f};
      float2v acc1 = {0.f, 0.f};
#pragma unroll
      for (int ky = 0; ky < 3; ++ky)
#pragma unroll
        for (int kx = 0; kx < 3; ++kx) {
          float w = wc[ky * 3 + kx];
          float2v wv2 = {w, w};
          float2v p0 = {p[ky][kx], p[ky][kx + 1]};
          float2v p1 = {p[1 + ky][kx], p[1 + ky][kx + 1]};
          acc0 = __builtin_elementwise_fma(wv2, p0, acc0);
          acc1 = __builtin_elementwise_fma(wv2, p1, acc1);
        }
      int c = 0;
      c += ((acc0[0] + bv) > 1.0f) ? 1 : 0;
      c += ((acc0[1] + bv) > 1.0f) ? 1 : 0;
      c += ((acc1[0] + bv) > 1.0f) ? 1 : 0;
      c += ((acc1[1] + bv) > 1.0f) ? 1 : 0;
      cin[(py * 18 + px + 1) * 40 + ch] = (_Float16)(float)c;
    }
  }
  __syncthreads();

  const int lane = t & 63;
  const int wave = __builtin_amdgcn_readfirstlane(t >> 6);
  const int xlane = lane & 15, quad = lane >> 4;

  float4v acc[4][4];
#pragma unroll
  for (int mt = 0; mt < 4; ++mt)
#pragma unroll
    for (int nt = 0; nt < 4; ++nt) acc[mt][nt] = (float4v){0.f, 0.f, 0.f, 0.f};

#pragma unroll
  for (int ky = 0; ky < 3; ++ky)
#pragma unroll
    for (int kx = 0; kx < 3; ++kx) {
      const int tp = ky * 3 + kx;
      half8 bfr[4];
#pragma unroll
      for (int nt = 0; nt < 4; ++nt) {
        int row = wave * 4 + nt + ky;
        int col = xlane + kx;
        bfr[nt] = *(const half8*)&cin[(row * 18 + col) * 40 + quad * 8];
      }
#pragma unroll
      for (int mt = 0; mt < 4; ++mt) {
        half8 ah = *(const half8*)(afrag +
                     ((size_t)((tp * 4 + mt) * 2 + 0)) * 512 + lane * 8);
        half8 al = *(const half8*)(afrag +
                     ((size_t)((tp * 4 + mt) * 2 + 1)) * 512 + lane * 8);
#pragma unroll
        for (int nt = 0; nt < 4; ++nt) {
          acc[mt][nt] = __builtin_amdgcn_mfma_f32_16x16x32_f16(ah, bfr[nt],
                                                               acc[mt][nt], 0, 0, 0);
          acc[mt][nt] = __builtin_amdgcn_mfma_f32_16x16x32_f16(al, bfr[nt],
                                                               acc[mt][nt], 0, 0, 0);
        }
      }
    }

  float bw[4][4];
#pragma unroll
  for (int mt = 0; mt < 4; ++mt)
#pragma unroll
    for (int r = 0; r < 4; ++r) bw[mt][r] = b2c[mt * 16 + quad * 4 + r];

  const int px = xlane >> 1;
  const bool writer = (xlane & 1) == 0;
#pragma unroll
  for (int mt = 0; mt < 4; ++mt)
#pragma unroll
    for (int ntp = 0; ntp < 2; ++ntp) {
      int py = wave * 2 + ntp;
#pragma unroll
      for (int r = 0; r < 4; ++r) {
        float v0 = 0.25f * acc[mt][2 * ntp + 0][r] + bw[mt][r];
        float v1 = 0.25f * acc[mt][2 * ntp + 1][r] + bw[mt][r];
        int c = ((v0 > 1.0f) ? 1 : 0) + ((v1 > 1.0f) ? 1 : 0);
        c += __shfl_xor(c, 1, 64);
        if (writer) {
          int oc = mt * 16 + quad * 4 + r;
          cnt[oc * 64 + py * 8 + px] = (uint8_t)c;
        }
      }
    }
  __syncthreads();

  {
    uint4 v = *(const uint4*)&cnt[(t >> 2) * 64 + (t & 3) * 16];
    *(uint4*)(xq + (size_t)s * 8192 + (size_t)(t >> 2) * 128 + h * 64 +
              (t & 3) * 16) = v;
  }
}

// ---------------------------------------------------------------- fc1 (MFMA)
// 64-sample tiles (R12 form). A-fragments (w1s) prefetched distance-1;
// hi/lo inline per lane. B staging uses the magic perm unpack.
__global__ __launch_bounds__(256, 2) void k_fc1(const uint8_t* __restrict__ xq,
                                                const _Float16* __restrict__ w1s,
                                                float* __restrict__ part) {
  __shared__ _Float16 bt[8 * 4 * 64 * 8];   // [kc][nt][lane][8] = 32 KB
  const int t = threadIdx.x;
  const int sblk = blockIdx.x >> 5;   // 16 sample tiles of 64
  const int kblk = blockIdx.x & 31;   // 32 K slices of 256
  const int sb = sblk * 64;

  {  // stage B: u8 counts -> fp16, frag-ready (magic perm)
    const int row = t >> 2;
    const int seg = t & 3;
    const int nt = row >> 4, n16 = row & 15;
    const uint8_t* src = xq + (size_t)(sb + row) * 8192 + kblk * 256 + seg * 64;
#pragma unroll
    for (int q = 0; q < 4; ++q) {
      uint4 u = *(const uint4*)(src + q * 16);
#pragma unroll
      for (int g = 0; g < 2; ++g) {
        half8 h = (g == 0) ? u8x8_to_h8(u.x, u.y) : u8x8_to_h8(u.z, u.w);
        int koff = seg * 64 + q * 16 + g * 8;
        int kc = koff >> 5, quad = (koff >> 3) & 3;
        *(half8*)&bt[(((kc * 4 + nt) * 64) + quad * 16 + n16) * 8] = h;
      }
    }
  }
  __syncthreads();

  const int lane = t & 63;
  const int wave = __builtin_amdgcn_readfirstlane(t >> 6);

  float4v acc[4][4];
#pragma unroll
  for (int mt = 0; mt < 4; ++mt)
#pragma unroll
    for (int nt = 0; nt < 4; ++nt) acc[mt][nt] = (float4v){0.f, 0.f, 0.f, 0.f};

  // W(kc,mt) = (wave*4+mt)*256 + kblk*8+kc ; layout [W][lane][16]
  const _Float16* wbase = w1s + ((size_t)(wave * 4) * 256 + kblk * 8) * 1024 + lane * 16;
  half8 a0 = *(const half8*)(wbase);
  half8 a1 = *(const half8*)(wbase + 8);
#pragma unroll
  for (int kc = 0; kc < 8; ++kc) {
    half8 b[4];
#pragma unroll
    for (int nt = 0; nt < 4; ++nt)
      b[nt] = *(const half8*)&bt[((kc * 4 + nt) * 64 + lane) * 8];
#pragma unroll
    for (int mt = 0; mt < 4; ++mt) {
      half8 n0, n1;
      if (!(kc == 7 && mt == 3)) {
        const int nk = (mt == 3) ? kc + 1 : kc;
        const int nm = (mt == 3) ? 0 : mt + 1;
        const _Float16* np = wbase + ((size_t)(nm * 256 + nk)) * 1024;
        n0 = *(const half8*)np;
        n1 = *(const half8*)(np + 8);
      } else { n0 = a0; n1 = a1; }
#pragma unroll
      for (int nt = 0; nt < 4; ++nt) {
        acc[mt][nt] = __builtin_amdgcn_mfma_f32_16x16x32_f16(a0, b[nt],
                                                             acc[mt][nt], 0, 0, 0);
        acc[mt][nt] = __builtin_amdgcn_mfma_f32_16x16x32_f16(a1, b[nt],
                                                             acc[mt][nt], 0, 0, 0);
      }
      a0 = n0; a1 = n1;
    }
  }

  const int n16 = lane & 15, quad = lane >> 4;
  float* pp = part + (size_t)kblk * (1024 * 256);
#pragma unroll
  for (int mt = 0; mt < 4; ++mt)
#pragma unroll
    for (int nt = 0; nt < 4; ++nt) {
      int s = sb + nt * 16 + n16;
      int ob = wave * 64 + mt * 16 + quad * 4;
      float4 v = {0.25f * acc[mt][nt][0], 0.25f * acc[mt][nt][1],
                  0.25f * acc[mt][nt][2], 0.25f * acc[mt][nt][3]};
      *(float4*)&pp[(size_t)s * 256 + ob] = v;
    }
}

// ---------------------------------------------------------------- LIF recurrence
// 4 samples/block, grid 256 (R12 form — measured optimum). Also performs the
// fc1 K-split reduction (part -> cur3, in LDS). 2 barriers/step (fc3 delayed
// one iteration). part loads batched into registers, summed in the SAME
// sequential kb order.
__global__ __launch_bounds__(512, 2) void k_lif(const float* __restrict__ part,
                                                const float* __restrict__ b1,
                                                const float* __restrict__ w2,   // [128][256]
                                                const float* __restrict__ b2,
                                                const float* __restrict__ w3,   // [10][128]
                                                const float* __restrict__ b3,
                                                float* __restrict__ out) {
  __shared__ float cur3l[1024];     // [s4][o256]
  __shared__ _Float16 spk3[1152];   // [oct32][s4][8] + pad
  __shared__ _Float16 spk4[640];    // [oct16][s4][8] + pad
  const int t = threadIdx.x;
  const int sb = blockIdx.x * 4;    // 4 samples/block, grid 256 = 1 block/CU
  const int lane = t & 63;
  const int wave = __builtin_amdgcn_readfirstlane(t >> 6);
  const int n16 = lane & 15;
  const int quad = lane >> 4;

  // ---- fc1 reduce: batched loads, deterministic kb-order sum + bias-last
#pragma unroll
  for (int r = 0; r < 2; ++r) {
    int v = t + r * 512;            // = s*256 + o
    int s = v >> 8, o = v & 255;
    const float* pb = part + (size_t)(sb + s) * 256 + o;
    float pv[32];
#pragma unroll
    for (int kb = 0; kb < 32; ++kb)
      pv[kb] = pb[(size_t)kb * (1024 * 256)];
    float sum = 0.0f;
#pragma unroll
    for (int kb = 0; kb < 32; ++kb) sum += pv[kb];
    cur3l[v] = sum + b1[o];
  }

  // ---- fc2 A-frags: A[m=lane&15][k=quad*8+jj], hi/lo exact split
  half8 a2h[8], a2l[8];
  {
    const float* wr = w2 + (size_t)(wave * 16 + n16) * 256 + quad * 8;
#pragma unroll
    for (int kt = 0; kt < 8; ++kt) {
      float4 u0 = *(const float4*)(wr + kt * 32);
      float4 u1 = *(const float4*)(wr + kt * 32 + 4);
      float wv[8] = {u0.x, u0.y, u0.z, u0.w, u1.x, u1.y, u1.z, u1.w};
#pragma unroll
      for (int e = 0; e < 8; ++e) {
        float hi = (float)(_Float16)wv[e];
        a2h[kt][e] = (_Float16)wv[e];
        a2l[kt][e] = (_Float16)(wv[e] - hi);
      }
    }
  }
  const float4 b2v = *(const float4*)(b2 + wave * 16 + quad * 4);
  float mem4[4] = {0.f, 0.f, 0.f, 0.f};

  // ---- fc3 A-frags (wave 0), rows >= 10 zero
  half8 a3h[4], a3l[4];
#pragma unroll
  for (int kt = 0; kt < 4; ++kt) { a3h[kt] = (half8){}; a3l[kt] = (half8){}; }
  if (n16 < 10) {
    const float* wr = w3 + (size_t)n16 * 128 + quad * 8;
#pragma unroll
    for (int kt = 0; kt < 4; ++kt) {
      float4 u0 = *(const float4*)(wr + kt * 32);
      float4 u1 = *(const float4*)(wr + kt * 32 + 4);
      float wv[8] = {u0.x, u0.y, u0.z, u0.w, u1.x, u1.y, u1.z, u1.w};
#pragma unroll
      for (int e = 0; e < 8; ++e) {
        float hi = (float)(_Float16)wv[e];
        a3h[kt][e] = (_Float16)wv[e];
        a3l[kt][e] = (_Float16)(wv[e] - hi);
      }
    }
  }
  float b3r[4];
#pragma unroll
  for (int r = 0; r < 4; ++r) {
    int cls = quad * 4 + r;
    b3r[r] = (cls < 10) ? b3[cls] : 0.0f;
  }
  float mem5[4] = {0.f, 0.f, 0.f, 0.f};

  __syncthreads();

  // ---- phase-1 state: threads 0..127, thread = (oct o = t>>2, sample s = t&3)
  float mem3[8], cur3r[8];
  if (t < 128) {
    const int o = t >> 2, s = t & 3;
    const float* cp = &cur3l[s * 256 + o * 8];
    float4 c0 = *(const float4*)cp;
    float4 c1 = *(const float4*)(cp + 4);
    cur3r[0] = c0.x; cur3r[1] = c0.y; cur3r[2] = c0.z; cur3r[3] = c0.w;
    cur3r[4] = c1.x; cur3r[5] = c1.y; cur3r[6] = c1.z; cur3r[7] = c1.w;
#pragma unroll
    for (int j = 0; j < 8; ++j) mem3[j] = 0.0f;
  }

  for (int step = 0; step < NSTEP; ++step) {
    // ---- fc3 for previous step (spk4[step-1] visible since barrier B)
    if (wave == 0 && step > 0) {
      float4v c0 = {0.f, 0.f, 0.f, 0.f}, c1 = {0.f, 0.f, 0.f, 0.f};
#pragma unroll
      for (int kt = 0; kt < 4; ++kt) {
        half8 b = *(const half8*)&spk4[(kt * 4 + quad) * 32 + n16 * 8];
        c0 = __builtin_amdgcn_mfma_f32_16x16x32_f16(a3h[kt], b, c0, 0, 0, 0);
        c1 = __builtin_amdgcn_mfma_f32_16x16x32_f16(a3l[kt], b, c1, 0, 0, 0);
      }
#pragma unroll
      for (int r = 0; r < 4; ++r) {
        int cls = quad * 4 + r;
        float cur5 = (c0[r] + c1[r]) + b3r[r];
        mem5[r] = lif_update(mem5[r], cur5);
        if (n16 < 4 && cls < 10)
          out[(size_t)(step - 1) * 10240 + (size_t)(sb + n16) * 10 + cls] =
              (mem5[r] > 1.0f) ? 1.0f : 0.0f;
      }
    }
    // ---- phase 1: mem3/spk3 (waves 0,1)
    if (t < 128) {
      const int o = t >> 2, s = t & 3;
      half8 sv;
#pragma unroll
      for (int j = 0; j < 8; ++j) {
        mem3[j] = lif_update(mem3[j], cur3r[j]);
        sv[j] = (_Float16)((mem3[j] > 1.0f) ? 1.0f : 0.0f);
      }
      *(half8*)&spk3[o * 32 + s * 8] = sv;
    }
    __syncthreads();   // A: spk3 visible; wave0 done reading spk4[step-1]
    {
      float4v acc0 = {0.f, 0.f, 0.f, 0.f}, acc1 = {0.f, 0.f, 0.f, 0.f};
#pragma unroll
      for (int kt = 0; kt < 8; ++kt) {
        half8 b = *(const half8*)&spk3[(kt * 4 + quad) * 32 + n16 * 8];
        acc0 = __builtin_amdgcn_mfma_f32_16x16x32_f16(a2h[kt], b, acc0, 0, 0, 0);
        acc1 = __builtin_amdgcn_mfma_f32_16x16x32_f16(a2l[kt], b, acc1, 0, 0, 0);
      }
      if (n16 < 4) {
        half4v pk;
#pragma unroll
        for (int r = 0; r < 4; ++r) {
          float cur4 = (acc0[r] + acc1[r]) + b2v[r];
          mem4[r] = lif_update(mem4[r], cur4);
          pk[r] = (_Float16)((mem4[r] > 1.0f) ? 1.0f : 0.0f);
        }
        *(half4v*)&spk4[(wave * 2 + (quad >> 1)) * 32 + n16 * 8 + (quad & 1) * 4] = pk;
      }
    }
    __syncthreads();   // B: spk4[step] visible
  }

  // ---- final fc3 (step NSTEP-1)
  if (wave == 0) {
    float4v c0 = {0.f, 0.f, 0.f, 0.f}, c1 = {0.f, 0.f, 0.f, 0.f};
#pragma unroll
    for (int kt = 0; kt < 4; ++kt) {
      half8 b = *(const half8*)&spk4[(kt * 4 + quad) * 32 + n16 * 8];
      c0 = __builtin_amdgcn_mfma_f32_16x16x32_f16(a3h[kt], b, c0, 0, 0, 0);
      c1 = __builtin_amdgcn_mfma_f32_16x16x32_f16(a3l[kt], b, c1, 0, 0, 0);
    }
#pragma unroll
    for (int r = 0; r < 4; ++r) {
      int cls = quad * 4 + r;
      float cur5 = (c0[r] + c1[r]) + b3r[r];
      mem5[r] = lif_update(mem5[r], cur5);
      if (n16 < 4 && cls < 10)
        out[(size_t)(NSTEP - 1) * 10240 + (size_t)(sb + n16) * 10 + cls] =
            (mem5[r] > 1.0f) ? 1.0f : 0.0f;
    }
  }
}

// ---------------------------------------------------------------- launcher
extern "C" void kernel_launch(void* const* d_in, const int* in_sizes, int n_in,
                              void* d_out, int out_size, void* d_ws, size_t ws_size,
                              hipStream_t stream) {
  (void)in_sizes; (void)n_in; (void)out_size; (void)ws_size;
  const float* x   = (const float*)d_in[0];
  const float* w1c = (const float*)d_in[1];
  const float* b1c = (const float*)d_in[2];
  const float* w2c = (const float*)d_in[3];
  const float* b2c = (const float*)d_in[4];
  const float* fw1 = (const float*)d_in[5];
  const float* fb1 = (const float*)d_in[6];
  const float* fw2 = (const float*)d_in[7];
  const float* fb2 = (const float*)d_in[8];
  const float* fw3 = (const float*)d_in[9];
  const float* fb3 = (const float*)d_in[10];
  float* out = (float*)d_out;

  char* ws = (char*)d_ws;
  float*    part  = (float*)ws;                       // 32 MB
  uint8_t*  xq    = (uint8_t*)(ws + (32u << 20));     //  8 MB
  _Float16* afrag = (_Float16*)(ws + (41u << 20));    // 72 KB
  _Float16* w1s   = (_Float16*)(ws + (42u << 20));    //  8 MB

  k_prep<<<dim3(72), dim3(256), 0, stream>>>(w2c, afrag);
  k_convf<<<dim3(3072), dim3(256), 0, stream>>>(x, w1c, b1c, afrag, b2c, xq,
                                                fw1, w1s);
  k_fc1<<<dim3(512), dim3(256), 0, stream>>>(xq, w1s, part);
  k_lif<<<dim3(256), dim3(512), 0, stream>>>(part, fb1, fw2, fb2, fw3, fb3, out);
}